// Round 1
// baseline (2312.191 us; speedup 1.0000x reference)
//
#include <hip/hip_runtime.h>
#include <math.h>

#define D 64
#define EDIM 16
#define NEG 0.2f

// monotonic float -> uint key (order-preserving), key 0 == minimum
__device__ __forceinline__ unsigned fkey(float f) {
    unsigned u = __float_as_uint(f);
    return (u & 0x80000000u) ? ~u : (u | 0x80000000u);
}
__device__ __forceinline__ float funkey(unsigned k) {
    unsigned u = (k & 0x80000000u) ? (k & 0x7FFFFFFFu) : ~k;
    return __uint_as_float(u);
}

// xl = x@Wl + bl ; xr = x@Wr + br ; res = x@Lw + Lb   (all D=64)
__global__ void node_transform(const float* __restrict__ x,
                               const float* __restrict__ Wl, const float* __restrict__ bl,
                               const float* __restrict__ Wr, const float* __restrict__ br,
                               const float* __restrict__ Lw, const float* __restrict__ Lb,
                               float* __restrict__ xl, float* __restrict__ xr,
                               float* __restrict__ res, int N)
{
    __shared__ float wl[D * D], wr[D * D], lw[D * D];
    __shared__ float xrow[4][D];
    for (int i = threadIdx.x; i < D * D; i += blockDim.x) {
        wl[i] = Wl[i]; wr[i] = Wr[i]; lw[i] = Lw[i];
    }
    __syncthreads();
    int lane = threadIdx.x & 63;
    int ln = threadIdx.x >> 6;  // 0..3 local node
    float vbl = bl[lane], vbr = br[lane], vlb = Lb[lane];
    for (int base = blockIdx.x * 4; base < N; base += gridDim.x * 4) {
        int n = base + ln;
        if (n < N) xrow[ln][lane] = x[(size_t)n * D + lane];
        __syncthreads();
        if (n < N) {
            float al = vbl, ar = vbr, ares = vlb;
            #pragma unroll
            for (int k = 0; k < D; k++) {
                float xv = xrow[ln][k];
                al   += xv * wl[k * D + lane];
                ar   += xv * wr[k * D + lane];
                ares += xv * lw[k * D + lane];
            }
            xl[(size_t)n * D + lane] = al;
            xr[(size_t)n * D + lane] = ar;
            res[(size_t)n * D + lane] = ares;
        }
        __syncthreads();
    }
}

// one wave per edge: s_e = dot(leakyrelu(xl[src]+xr[dst]+ea@We), a); atomicMax into smax[dst]
__global__ void edge_logits(const int* __restrict__ ei, const float* __restrict__ eattr,
                            const float* __restrict__ We, const float* __restrict__ avec,
                            const float* __restrict__ xl, const float* __restrict__ xr,
                            float* __restrict__ s, unsigned* __restrict__ smax, int E)
{
    __shared__ float we[EDIM * D];
    __shared__ float av[D];
    for (int i = threadIdx.x; i < EDIM * D; i += blockDim.x) we[i] = We[i];
    if (threadIdx.x < D) av[threadIdx.x] = avec[threadIdx.x];
    __syncthreads();
    int wid = (int)((blockIdx.x * (size_t)blockDim.x + threadIdx.x) >> 6);
    int lane = threadIdx.x & 63;
    if (wid >= E) return;
    int src = ei[wid];
    int dst = ei[E + wid];
    const float* ea = eattr + (size_t)wid * EDIM;
    float ew = 0.f;
    #pragma unroll
    for (int k = 0; k < EDIM; k++) ew += ea[k] * we[k * D + lane];
    float m = xl[(size_t)src * D + lane] + xr[(size_t)dst * D + lane] + ew;
    float lr = m > 0.f ? m : NEG * m;
    float p = lr * av[lane];
    #pragma unroll
    for (int off = 32; off > 0; off >>= 1) p += __shfl_xor(p, off);
    if (lane == 0) {
        s[wid] = p;
        atomicMax(smax + dst, fkey(p));
    }
}

// one thread per edge: ex = exp(s - smax[dst]); den[dst] += ex; s <- ex
__global__ void edge_softmax_den(const int* __restrict__ ei, const unsigned* __restrict__ smax,
                                 float* __restrict__ s, float* __restrict__ den, int E)
{
    int e = blockIdx.x * blockDim.x + threadIdx.x;
    if (e >= E) return;
    int dst = ei[E + e];
    float mx = funkey(smax[dst]);
    float ex = __expf(s[e] - mx);
    s[e] = ex;
    atomicAdd(den + dst, ex);
}

// one wave per edge: agg[dst] += (ex/den[dst]) * xl[src]
__global__ void edge_aggregate(const int* __restrict__ ei, const float* __restrict__ s,
                               const float* __restrict__ den, const float* __restrict__ xl,
                               float* __restrict__ agg, int E)
{
    int wid = (int)((blockIdx.x * (size_t)blockDim.x + threadIdx.x) >> 6);
    int lane = threadIdx.x & 63;
    if (wid >= E) return;
    int src = ei[wid];
    int dst = ei[E + wid];
    float alpha = s[wid] / (den[dst] + 1e-16f);
    atomicAdd(agg + (size_t)dst * D + lane, alpha * xl[(size_t)src * D + lane]);
}

// out = (agg + cb + res), optional relu
__global__ void finish(const float* __restrict__ agg, const float* __restrict__ cb,
                       const float* __restrict__ res, float* __restrict__ out,
                       int total, int do_relu)
{
    int i = blockIdx.x * blockDim.x + threadIdx.x;
    if (i >= total) return;
    float v = agg[i] + cb[i & (D - 1)] + res[i];
    if (do_relu) v = fmaxf(v, 0.f);
    out[i] = v;
}

extern "C" void kernel_launch(void* const* d_in, const int* in_sizes, int n_in,
                              void* d_out, int out_size, void* d_ws, size_t ws_size,
                              hipStream_t stream)
{
    const float* x     = (const float*)d_in[0];
    const int*   ei    = (const int*)d_in[1];
    const float* eattr = (const float*)d_in[2];
    const float* Wl1 = (const float*)d_in[3];  const float* bl1 = (const float*)d_in[4];
    const float* Wr1 = (const float*)d_in[5];  const float* br1 = (const float*)d_in[6];
    const float* We1 = (const float*)d_in[7];  const float* a1  = (const float*)d_in[8];
    const float* cb1 = (const float*)d_in[9];
    const float* L1w = (const float*)d_in[10]; const float* L1b = (const float*)d_in[11];
    const float* Wl2 = (const float*)d_in[12]; const float* bl2 = (const float*)d_in[13];
    const float* Wr2 = (const float*)d_in[14]; const float* br2 = (const float*)d_in[15];
    const float* We2 = (const float*)d_in[16]; const float* a2  = (const float*)d_in[17];
    const float* cb2 = (const float*)d_in[18];
    const float* L2w = (const float*)d_in[19]; const float* L2b = (const float*)d_in[20];

    const int N = in_sizes[0] / D;
    const int E = in_sizes[1] / 2;

    float* ws = (float*)d_ws;
    float* xl  = ws; ws += (size_t)N * D;
    float* xr  = ws; ws += (size_t)N * D;
    float* res = ws; ws += (size_t)N * D;
    float* h   = ws; ws += (size_t)N * D;
    float* s   = ws; ws += E;
    unsigned* smax = (unsigned*)ws; ws += N;
    float* den = ws; ws += N;

    float* out = (float*)d_out;

    const int eb = (E + 3) / 4;          // edge wave-kernels: 4 edges/block
    const int et = (E + 255) / 256;      // edge thread-kernels
    const int nt = (N * D + 255) / 256;  // node-element kernels

    // ---------------- layer 1 ----------------
    hipMemsetAsync(out, 0, (size_t)N * D * sizeof(float), stream);
    hipMemsetAsync(smax, 0, (size_t)N * sizeof(unsigned), stream);
    hipMemsetAsync(den, 0, (size_t)N * sizeof(float), stream);
    node_transform<<<2048, 256, 0, stream>>>(x, Wl1, bl1, Wr1, br1, L1w, L1b,
                                             xl, xr, res, N);
    edge_logits<<<eb, 256, 0, stream>>>(ei, eattr, We1, a1, xl, xr, s, smax, E);
    edge_softmax_den<<<et, 256, 0, stream>>>(ei, smax, s, den, E);
    edge_aggregate<<<eb, 256, 0, stream>>>(ei, s, den, xl, out, E);
    finish<<<nt, 256, 0, stream>>>(out, cb1, res, h, N * D, 1);

    // ---------------- layer 2 ----------------
    hipMemsetAsync(out, 0, (size_t)N * D * sizeof(float), stream);
    hipMemsetAsync(smax, 0, (size_t)N * sizeof(unsigned), stream);
    hipMemsetAsync(den, 0, (size_t)N * sizeof(float), stream);
    node_transform<<<2048, 256, 0, stream>>>(h, Wl2, bl2, Wr2, br2, L2w, L2b,
                                             xl, xr, res, N);
    edge_logits<<<eb, 256, 0, stream>>>(ei, eattr, We2, a2, xl, xr, s, smax, E);
    edge_softmax_den<<<et, 256, 0, stream>>>(ei, smax, s, den, E);
    edge_aggregate<<<eb, 256, 0, stream>>>(ei, s, den, xl, out, E);
    finish<<<nt, 256, 0, stream>>>(out, cb2, res, h == out ? out : out, N * D, 0);
}

// Round 2
// 1371.402 us; speedup vs baseline: 1.6860x; 1.6860x over previous
//
#include <hip/hip_runtime.h>
#include <math.h>

#define D 64
#define EDIM 16
#define NEG 0.2f
#define SCAN_T 1024

// xl = x@Wl + bl ; xr = x@Wr + br ; res = x@Lw + Lb   (all D=64)
__global__ void node_transform(const float* __restrict__ x,
                               const float* __restrict__ Wl, const float* __restrict__ bl,
                               const float* __restrict__ Wr, const float* __restrict__ br,
                               const float* __restrict__ Lw, const float* __restrict__ Lb,
                               float* __restrict__ xl, float* __restrict__ xr,
                               float* __restrict__ res, int N)
{
    __shared__ float wl[D * D], wr[D * D], lw[D * D];
    __shared__ float xrow[4][D];
    for (int i = threadIdx.x; i < D * D; i += blockDim.x) {
        wl[i] = Wl[i]; wr[i] = Wr[i]; lw[i] = Lw[i];
    }
    __syncthreads();
    int lane = threadIdx.x & 63;
    int ln = threadIdx.x >> 6;  // 0..3 local node
    float vbl = bl[lane], vbr = br[lane], vlb = Lb[lane];
    for (int base = blockIdx.x * 4; base < N; base += gridDim.x * 4) {
        int n = base + ln;
        if (n < N) xrow[ln][lane] = x[(size_t)n * D + lane];
        __syncthreads();
        if (n < N) {
            float al = vbl, ar = vbr, ares = vlb;
            #pragma unroll
            for (int k = 0; k < D; k++) {
                float xv = xrow[ln][k];
                al   += xv * wl[k * D + lane];
                ar   += xv * wr[k * D + lane];
                ares += xv * lw[k * D + lane];
            }
            xl[(size_t)n * D + lane] = al;
            xr[(size_t)n * D + lane] = ar;
            res[(size_t)n * D + lane] = ares;
        }
        __syncthreads();
    }
}

__global__ void count_deg(const int* __restrict__ ei, int* __restrict__ deg, int E)
{
    int e = blockIdx.x * blockDim.x + threadIdx.x;
    if (e < E) atomicAdd(&deg[ei[E + e]], 1);
}

// single-block exclusive scan of deg[0..N) -> rowptr[0..N]
__global__ void scan_rowptr(const int* __restrict__ deg, int* __restrict__ rowptr, int N)
{
    __shared__ int part[SCAN_T];
    int t = threadIdx.x;
    int C = (N + SCAN_T - 1) / SCAN_T;
    int b = t * C, e = min(b + C, N);
    int sum = 0;
    for (int i = b; i < e; i++) sum += deg[i];
    part[t] = sum;
    __syncthreads();
    for (int off = 1; off < SCAN_T; off <<= 1) {
        int x = (t >= off) ? part[t - off] : 0;
        __syncthreads();
        part[t] += x;
        __syncthreads();
    }
    int running = part[t] - sum;  // exclusive offset for this thread's chunk
    for (int i = b; i < e; i++) {
        rowptr[i] = running;
        running += deg[i];
    }
    if (t == 0) rowptr[N] = part[SCAN_T - 1];
}

__global__ void scatter_edges(const int* __restrict__ ei, int* __restrict__ cursor,
                              int* __restrict__ esrc, int* __restrict__ eidx, int E)
{
    int e = blockIdx.x * blockDim.x + threadIdx.x;
    if (e >= E) return;
    int dst = ei[E + e];
    int pos = atomicAdd(&cursor[dst], 1);
    esrc[pos] = ei[e];
    eidx[pos] = e;
}

// one wave per dst node; online softmax over its incoming edges; fully fused
__global__ void gat_fused(const int* __restrict__ rowptr, const int* __restrict__ esrc,
                          const int* __restrict__ eidx,
                          const float* __restrict__ eattr, const float* __restrict__ We,
                          const float* __restrict__ avec,
                          const float* __restrict__ xl, const float* __restrict__ xr,
                          const float* __restrict__ res, const float* __restrict__ cb,
                          float* __restrict__ out, int N, int do_relu)
{
    __shared__ float we[EDIM * D];
    for (int i = threadIdx.x; i < EDIM * D; i += blockDim.x) we[i] = We[i];
    __syncthreads();
    int wid = (int)((blockIdx.x * (size_t)blockDim.x + threadIdx.x) >> 6);
    int lane = threadIdx.x & 63;
    if (wid >= N) return;
    int dst = wid;

    float xrv = xr[(size_t)dst * D + lane];
    float av = avec[lane];
    int beg = rowptr[dst], end = rowptr[dst + 1];

    float M = -INFINITY, S = 0.f, O = 0.f;
    for (int e = beg; e < end; ++e) {
        int src = esrc[e];
        int id  = eidx[e];
        float xlv = xl[(size_t)src * D + lane];
        float ea  = eattr[(size_t)id * EDIM + (lane & (EDIM - 1))];
        float ew = 0.f;
        #pragma unroll
        for (int k = 0; k < EDIM; k++)
            ew += __shfl(ea, k, EDIM) * we[k * D + lane];
        float m = xlv + xrv + ew;
        float lr = m > 0.f ? m : NEG * m;
        float p = lr * av;
        #pragma unroll
        for (int off = 32; off > 0; off >>= 1) p += __shfl_xor(p, off);
        if (p > M) {
            float sc = __expf(M - p);   // exp(-inf)=0 on first edge
            S *= sc; O *= sc; M = p;
        }
        float w = __expf(p - M);
        S += w;
        O += w * xlv;
    }
    float v = O / (S + 1e-16f) + cb[lane] + res[(size_t)dst * D + lane];
    if (do_relu) v = fmaxf(v, 0.f);
    out[(size_t)dst * D + lane] = v;
}

extern "C" void kernel_launch(void* const* d_in, const int* in_sizes, int n_in,
                              void* d_out, int out_size, void* d_ws, size_t ws_size,
                              hipStream_t stream)
{
    const float* x     = (const float*)d_in[0];
    const int*   ei    = (const int*)d_in[1];
    const float* eattr = (const float*)d_in[2];
    const float* Wl1 = (const float*)d_in[3];  const float* bl1 = (const float*)d_in[4];
    const float* Wr1 = (const float*)d_in[5];  const float* br1 = (const float*)d_in[6];
    const float* We1 = (const float*)d_in[7];  const float* a1  = (const float*)d_in[8];
    const float* cb1 = (const float*)d_in[9];
    const float* L1w = (const float*)d_in[10]; const float* L1b = (const float*)d_in[11];
    const float* Wl2 = (const float*)d_in[12]; const float* bl2 = (const float*)d_in[13];
    const float* Wr2 = (const float*)d_in[14]; const float* br2 = (const float*)d_in[15];
    const float* We2 = (const float*)d_in[16]; const float* a2  = (const float*)d_in[17];
    const float* cb2 = (const float*)d_in[18];
    const float* L2w = (const float*)d_in[19]; const float* L2b = (const float*)d_in[20];

    const int N = in_sizes[0] / D;
    const int E = in_sizes[1] / 2;

    char* wsb = (char*)d_ws;
    float* xl   = (float*)wsb; wsb += (size_t)N * D * sizeof(float);
    float* xr   = (float*)wsb; wsb += (size_t)N * D * sizeof(float);
    float* res  = (float*)wsb; wsb += (size_t)N * D * sizeof(float);
    int* deg    = (int*)wsb;   wsb += (size_t)N * sizeof(int);
    int* rowptr = (int*)wsb;   wsb += (size_t)(N + 1) * sizeof(int);
    int* cursor = (int*)wsb;   wsb += (size_t)N * sizeof(int);
    int* esrc   = (int*)wsb;   wsb += (size_t)E * sizeof(int);
    int* eidx   = (int*)wsb;   wsb += (size_t)E * sizeof(int);

    float* out = (float*)d_out;   // doubles as h between layers

    const int et = (E + 255) / 256;
    const int nb = (N + 3) / 4;   // 4 waves (dst nodes) per 256-thread block

    // ---------------- CSR build (shared by both layers) ----------------
    hipMemsetAsync(deg, 0, (size_t)N * sizeof(int), stream);
    count_deg<<<et, 256, 0, stream>>>(ei, deg, E);
    scan_rowptr<<<1, SCAN_T, 0, stream>>>(deg, rowptr, N);
    hipMemcpyAsync(cursor, rowptr, (size_t)N * sizeof(int),
                   hipMemcpyDeviceToDevice, stream);
    scatter_edges<<<et, 256, 0, stream>>>(ei, cursor, esrc, eidx, E);

    // ---------------- layer 1 ----------------
    node_transform<<<2048, 256, 0, stream>>>(x, Wl1, bl1, Wr1, br1, L1w, L1b,
                                             xl, xr, res, N);
    gat_fused<<<nb, 256, 0, stream>>>(rowptr, esrc, eidx, eattr, We1, a1,
                                      xl, xr, res, cb1, out, N, 1);

    // ---------------- layer 2 (reads layer-1 result from d_out) ----------------
    node_transform<<<2048, 256, 0, stream>>>(out, Wl2, bl2, Wr2, br2, L2w, L2b,
                                             xl, xr, res, N);
    gat_fused<<<nb, 256, 0, stream>>>(rowptr, esrc, eidx, eattr, We2, a2,
                                      xl, xr, res, cb2, out, N, 0);
}

// Round 3
// 1003.871 us; speedup vs baseline: 2.3033x; 1.3661x over previous
//
#include <hip/hip_runtime.h>
#include <math.h>

#define D 64
#define EDIM 16
#define NEG 0.2f
#define SCAN_T 1024

// xl = x@Wl + bl ; xr = x@Wr + br ; res = x@Lw + Lb   (all D=64)
// 8 rows per wave: per k-step 3 W-reads + 8 x-broadcasts feed 24 FMAs.
__global__ void node_transform(const float* __restrict__ x,
                               const float* __restrict__ Wl, const float* __restrict__ bl,
                               const float* __restrict__ Wr, const float* __restrict__ br,
                               const float* __restrict__ Lw, const float* __restrict__ Lb,
                               float* __restrict__ xl, float* __restrict__ xr,
                               float* __restrict__ res, int N)
{
    __shared__ float wl[D * D], wr[D * D], lw[D * D];
    __shared__ float xs[32][D];
    // stage weights as float4
    for (int i = threadIdx.x; i < D * D / 4; i += blockDim.x) {
        ((float4*)wl)[i] = ((const float4*)Wl)[i];
        ((float4*)wr)[i] = ((const float4*)Wr)[i];
        ((float4*)lw)[i] = ((const float4*)Lw)[i];
    }
    int lane = threadIdx.x & 63;
    int wave = threadIdx.x >> 6;          // 0..3, each wave owns 8 rows
    float vbl = bl[lane], vbr = br[lane], vlb = Lb[lane];
    __syncthreads();

    for (int base = blockIdx.x * 32; base < N; base += gridDim.x * 32) {
        int nrows = min(32, N - base);
        for (int i = threadIdx.x; i < nrows * D; i += blockDim.x)
            ((float*)xs)[i] = x[(size_t)base * D + i];
        __syncthreads();

        int r0 = wave * 8;
        if (base + r0 < N) {
            float al[8], ar[8], ae[8];
            #pragma unroll
            for (int j = 0; j < 8; j++) { al[j] = vbl; ar[j] = vbr; ae[j] = vlb; }
            #pragma unroll 4
            for (int k = 0; k < D; k++) {
                float w1 = wl[k * D + lane];
                float w2 = wr[k * D + lane];
                float w3 = lw[k * D + lane];
                #pragma unroll
                for (int j = 0; j < 8; j++) {
                    float xv = xs[r0 + j][k];
                    al[j] = fmaf(xv, w1, al[j]);
                    ar[j] = fmaf(xv, w2, ar[j]);
                    ae[j] = fmaf(xv, w3, ae[j]);
                }
            }
            #pragma unroll
            for (int j = 0; j < 8; j++) {
                int n = base + r0 + j;
                if (n < N) {
                    xl[(size_t)n * D + lane]  = al[j];
                    xr[(size_t)n * D + lane]  = ar[j];
                    res[(size_t)n * D + lane] = ae[j];
                }
            }
        }
        __syncthreads();
    }
}

__global__ void count_deg(const int* __restrict__ ei, int* __restrict__ deg, int E)
{
    int e = blockIdx.x * blockDim.x + threadIdx.x;
    if (e < E) atomicAdd(&deg[ei[E + e]], 1);
}

// single-block exclusive scan of deg[0..N) -> rowptr[0..N]
__global__ void scan_rowptr(const int* __restrict__ deg, int* __restrict__ rowptr, int N)
{
    __shared__ int part[SCAN_T];
    int t = threadIdx.x;
    int C = (N + SCAN_T - 1) / SCAN_T;
    int b = t * C, e = min(b + C, N);
    int sum = 0;
    for (int i = b; i < e; i++) sum += deg[i];
    part[t] = sum;
    __syncthreads();
    for (int off = 1; off < SCAN_T; off <<= 1) {
        int x = (t >= off) ? part[t - off] : 0;
        __syncthreads();
        part[t] += x;
        __syncthreads();
    }
    int running = part[t] - sum;
    for (int i = b; i < e; i++) {
        rowptr[i] = running;
        running += deg[i];
    }
    if (t == 0) rowptr[N] = part[SCAN_T - 1];
}

__global__ void scatter_edges(const int* __restrict__ ei, int* __restrict__ cursor,
                              int* __restrict__ esrc, int* __restrict__ eidx, int E)
{
    int e = blockIdx.x * blockDim.x + threadIdx.x;
    if (e >= E) return;
    int dst = ei[E + e];
    int pos = atomicAdd(&cursor[dst], 1);
    esrc[pos] = ei[e];
    eidx[pos] = e;
}

// one wave per dst node; online softmax; We column held in 16 registers,
// ea broadcast via uniform float4 loads -> only DS ops left are the 6-shfl reduce.
__global__ void gat_fused(const int* __restrict__ rowptr, const int* __restrict__ esrc,
                          const int* __restrict__ eidx,
                          const float* __restrict__ eattr, const float* __restrict__ We,
                          const float* __restrict__ avec,
                          const float* __restrict__ xl, const float* __restrict__ xr,
                          const float* __restrict__ res, const float* __restrict__ cb,
                          float* __restrict__ out, int N, int do_relu)
{
    int wid = (int)((blockIdx.x * (size_t)blockDim.x + threadIdx.x) >> 6);
    int lane = threadIdx.x & 63;
    if (wid >= N) return;
    int dst = wid;

    float wreg[EDIM];
    #pragma unroll
    for (int k = 0; k < EDIM; k++) wreg[k] = We[k * D + lane];
    float av  = avec[lane];
    float xrv = xr[(size_t)dst * D + lane];
    int beg = rowptr[dst], end = rowptr[dst + 1];

    float M = -INFINITY, S = 0.f, O = 0.f;
    for (int e = beg; e < end; ++e) {
        int src = esrc[e];
        int id  = eidx[e];
        float xlv = xl[(size_t)src * D + lane];
        const float4* ea4 = (const float4*)(eattr + (size_t)id * EDIM);
        float4 a0 = ea4[0], a1 = ea4[1], a2 = ea4[2], a3 = ea4[3];
        float ew;
        ew = a0.x * wreg[0];
        ew = fmaf(a0.y, wreg[1], ew);  ew = fmaf(a0.z, wreg[2], ew);
        ew = fmaf(a0.w, wreg[3], ew);  ew = fmaf(a1.x, wreg[4], ew);
        ew = fmaf(a1.y, wreg[5], ew);  ew = fmaf(a1.z, wreg[6], ew);
        ew = fmaf(a1.w, wreg[7], ew);  ew = fmaf(a2.x, wreg[8], ew);
        ew = fmaf(a2.y, wreg[9], ew);  ew = fmaf(a2.z, wreg[10], ew);
        ew = fmaf(a2.w, wreg[11], ew); ew = fmaf(a3.x, wreg[12], ew);
        ew = fmaf(a3.y, wreg[13], ew); ew = fmaf(a3.z, wreg[14], ew);
        ew = fmaf(a3.w, wreg[15], ew);
        float m = xlv + xrv + ew;
        float lr = fmaxf(m, 0.f) + NEG * fminf(m, 0.f);
        float p = lr * av;
        #pragma unroll
        for (int off = 32; off > 0; off >>= 1) p += __shfl_xor(p, off);
        if (p > M) {
            float sc = __expf(M - p);   // exp(-inf)=0 on first edge
            S *= sc; O *= sc; M = p;
        }
        float w = __expf(p - M);
        S += w;
        O = fmaf(w, xlv, O);
    }
    float v = O / (S + 1e-16f) + cb[lane] + res[(size_t)dst * D + lane];
    if (do_relu) v = fmaxf(v, 0.f);
    out[(size_t)dst * D + lane] = v;
}

extern "C" void kernel_launch(void* const* d_in, const int* in_sizes, int n_in,
                              void* d_out, int out_size, void* d_ws, size_t ws_size,
                              hipStream_t stream)
{
    const float* x     = (const float*)d_in[0];
    const int*   ei    = (const int*)d_in[1];
    const float* eattr = (const float*)d_in[2];
    const float* Wl1 = (const float*)d_in[3];  const float* bl1 = (const float*)d_in[4];
    const float* Wr1 = (const float*)d_in[5];  const float* br1 = (const float*)d_in[6];
    const float* We1 = (const float*)d_in[7];  const float* a1  = (const float*)d_in[8];
    const float* cb1 = (const float*)d_in[9];
    const float* L1w = (const float*)d_in[10]; const float* L1b = (const float*)d_in[11];
    const float* Wl2 = (const float*)d_in[12]; const float* bl2 = (const float*)d_in[13];
    const float* Wr2 = (const float*)d_in[14]; const float* br2 = (const float*)d_in[15];
    const float* We2 = (const float*)d_in[16]; const float* a2  = (const float*)d_in[17];
    const float* cb2 = (const float*)d_in[18];
    const float* L2w = (const float*)d_in[19]; const float* L2b = (const float*)d_in[20];

    const int N = in_sizes[0] / D;
    const int E = in_sizes[1] / 2;

    char* wsb = (char*)d_ws;
    float* xl   = (float*)wsb; wsb += (size_t)N * D * sizeof(float);
    float* xr   = (float*)wsb; wsb += (size_t)N * D * sizeof(float);
    float* res  = (float*)wsb; wsb += (size_t)N * D * sizeof(float);
    int* deg    = (int*)wsb;   wsb += (size_t)N * sizeof(int);
    int* rowptr = (int*)wsb;   wsb += (size_t)(N + 1) * sizeof(int);
    int* cursor = (int*)wsb;   wsb += (size_t)N * sizeof(int);
    int* esrc   = (int*)wsb;   wsb += (size_t)E * sizeof(int);
    int* eidx   = (int*)wsb;   wsb += (size_t)E * sizeof(int);

    float* out = (float*)d_out;   // doubles as h between layers

    const int et = (E + 255) / 256;
    const int nb = (N + 3) / 4;   // 4 dst waves per 256-thread block

    // ---------------- CSR build (shared by both layers) ----------------
    hipMemsetAsync(deg, 0, (size_t)N * sizeof(int), stream);
    count_deg<<<et, 256, 0, stream>>>(ei, deg, E);
    scan_rowptr<<<1, SCAN_T, 0, stream>>>(deg, rowptr, N);
    hipMemcpyAsync(cursor, rowptr, (size_t)N * sizeof(int),
                   hipMemcpyDeviceToDevice, stream);
    scatter_edges<<<et, 256, 0, stream>>>(ei, cursor, esrc, eidx, E);

    // ---------------- layer 1 ----------------
    node_transform<<<1024, 256, 0, stream>>>(x, Wl1, bl1, Wr1, br1, L1w, L1b,
                                             xl, xr, res, N);
    gat_fused<<<nb, 256, 0, stream>>>(rowptr, esrc, eidx, eattr, We1, a1,
                                      xl, xr, res, cb1, out, N, 1);

    // ---------------- layer 2 (reads layer-1 result from d_out) ----------------
    node_transform<<<1024, 256, 0, stream>>>(out, Wl2, bl2, Wr2, br2, L2w, L2b,
                                             xl, xr, res, N);
    gat_fused<<<nb, 256, 0, stream>>>(rowptr, esrc, eidx, eattr, We2, a2,
                                      xl, xr, res, cb2, out, N, 0);
}